// Round 3
// baseline (434.900 us; speedup 1.0000x reference)
//
#include <hip/hip_runtime.h>
#include <hip/hip_bf16.h>
#include <stdint.h>

typedef unsigned int u32;
typedef unsigned short u16;

#define F 128

typedef __attribute__((ext_vector_type(8))) short bf16x8;
typedef __attribute__((ext_vector_type(8))) u16 u16x8;
typedef __attribute__((ext_vector_type(4))) float f32x4;

__device__ __forceinline__ float bf2f(u16 v){
  union { u32 u; float f; } x; x.u = ((u32)v) << 16; return x.f;
}
__device__ __forceinline__ float bflo(u32 w){
  union { u32 u; float f; } x; x.u = w << 16; return x.f;       // 1 VALU
}
__device__ __forceinline__ float bfhi(u32 w){
  union { u32 u; float f; } x; x.u = w & 0xFFFF0000u; return x.f; // 1 VALU
}
__device__ __forceinline__ u16 f2bf(float f){
  union { float f; u32 u; } x; x.f = f;
  u32 u = x.u;
  return (u16)((u + 0x7fffu + ((u >> 16) & 1u)) >> 16);   // RNE
}

// ---- merged dtype / edge-layout detection -----------------------------------
__global__ void k_flags(const u32* __restrict__ xw, const u32* __restrict__ ei,
                        int* __restrict__ flags){
  if (blockIdx.x == 0){
    u32 hit = 0;
    for (int i = threadIdx.x; i < 2048; i += 256){
      u32 e = (xw[i] >> 7) & 0xFFu;
      if (e > 160u) hit = 1;
    }
    if (hit) atomicOr(&flags[1], 1);
  } else {
    u32 v = 0;
    for (int i = threadIdx.x; i < 4096; i += 256) v |= ei[2*i + 1];
    if (v) atomicOr(&flags[0], 1);
  }
}

// ---- bucketed CSR build (256-node buckets) ----------------------------------
__launch_bounds__(256)
__global__ void k_bhist(const u32* __restrict__ w, int E, const int* __restrict__ flagp,
                        int NB, int* __restrict__ bcnt){
  __shared__ int h[256];
  int st = (*flagp) ? 1 : 2;
  int t = threadIdx.x;
  h[t] = 0;
  __syncthreads();
  int base = blockIdx.x*4096;
  #pragma unroll 4
  for (int k = 0; k < 16; k++){
    int i = base + k*256 + t;
    if (i < E){
      int d = (int)w[(size_t)(E + i)*st];
      atomicAdd(&h[d >> 8], 1);
    }
  }
  __syncthreads();
  if (t < NB && h[t]) atomicAdd(&bcnt[t], h[t]);
}

__global__ void k_bscan(const int* __restrict__ bcnt, int NB, int E,
                        int* __restrict__ bbase, int* __restrict__ bump){
  __shared__ int s[256];
  int t = threadIdx.x;
  int v = (t < NB) ? bcnt[t] : 0;
  s[t] = v;
  __syncthreads();
  for (int off = 1; off < 256; off <<= 1){
    int x = (t >= off) ? s[t - off] : 0;
    __syncthreads();
    s[t] += x;
    __syncthreads();
  }
  bbase[t] = s[t] - v;            // exclusive; == E for t >= NB
  if (t == 255) bbase[256] = E;
  bump[t] = 0;
}

__launch_bounds__(256)
__global__ void k_msplit(const u32* __restrict__ w, int E, const int* __restrict__ flagp,
                         const int* __restrict__ bbase, int* __restrict__ bump,
                         u32* __restrict__ ebuf){
  __shared__ int h[256];
  __shared__ int cb[256];
  int st = (*flagp) ? 1 : 2;
  int t = threadIdx.x;
  h[t] = 0;
  __syncthreads();
  int base = blockIdx.x*4096;
  u32 ps[16]; int bk[16]; int rk[16];
  #pragma unroll 4
  for (int k = 0; k < 16; k++){
    int i = base + k*256 + t;
    if (i < E){
      u32 s = w[(size_t)i*st];
      u32 d = w[(size_t)(E + i)*st];
      bk[k] = (int)(d >> 8);
      ps[k] = (s & 0xFFFFu) | ((d & 0xFFu) << 16);
      rk[k] = atomicAdd(&h[bk[k]], 1);
    } else bk[k] = -1;
  }
  __syncthreads();
  cb[t] = h[t] ? (bbase[t] + atomicAdd(&bump[t], h[t])) : 0;
  __syncthreads();
  #pragma unroll 4
  for (int k = 0; k < 16; k++){
    if (bk[k] >= 0) ebuf[cb[bk[k]] + rk[k]] = ps[k];
  }
}

// per-bucket deg/rs/csr emit + dis = rsqrt(1+deg) folded in
__launch_bounds__(256)
__global__ void k_bemit(const u32* __restrict__ ebuf, const int* __restrict__ bbase,
                        int N, int* __restrict__ deg, int* __restrict__ rs,
                        u16* __restrict__ csr, float* __restrict__ dis){
  __shared__ int nd[256];
  __shared__ int nofs[256];
  __shared__ int s[256];
  int b = blockIdx.x;
  int t = threadIdx.x;
  int e0 = bbase[b], e1 = bbase[b + 1];
  nd[t] = 0;
  __syncthreads();
  for (int i = e0 + t; i < e1; i += 256) atomicAdd(&nd[ebuf[i] >> 16], 1);
  __syncthreads();
  int v = nd[t];
  s[t] = v;
  __syncthreads();
  for (int off = 1; off < 256; off <<= 1){
    int x = (t >= off) ? s[t - off] : 0;
    __syncthreads();
    s[t] += x;
    __syncthreads();
  }
  nofs[t] = s[t] - v;
  int node = b*256 + t;
  if (node < N){
    deg[node] = v;
    rs[node]  = e0 + nofs[t];
    dis[node] = rsqrtf(1.0f + (float)v);
  }
  nd[t] = 0;               // reuse as fill
  __syncthreads();
  for (int i = e0 + t; i < e1; i += 256){
    u32 p = ebuf[i];
    int d = (int)(p >> 16);
    int pos = e0 + nofs[d] + atomicAdd(&nd[d], 1);
    csr[pos] = (u16)(p & 0xFFFFu);
  }
}

// ---- merged small-tensor prep: bb[3][128], wf4[128], bb4[1] -----------------
__global__ void k_prep(const void* b1, const void* b2, const void* b3,
                       const void* W4, const void* b4, const int* __restrict__ isf32,
                       float* __restrict__ bb, float* __restrict__ wf4,
                       float* __restrict__ bb4){
  int t = threadIdx.x;
  int f32 = *isf32;
  if (t < 384){
    const void* s = (t < 128) ? b1 : ((t < 256) ? b2 : b3);
    int i = t & 127;
    bb[t] = f32 ? ((const float*)s)[i] : bf2f(((const u16*)s)[i]);
  } else if (t < 512){
    int i = t - 384;
    wf4[i] = f32 ? ((const float*)W4)[i] : bf2f(((const u16*)W4)[i]);
  } else if (t == 512){
    bb4[0] = f32 ? ((const float*)b4)[0] : bf2f(((const u16*)b4)[0]);
  }
}

// dual-dtype input -> bf16 in SLICED layout X_t[c][r][32]; thread = 8 feats
__global__ void k_cvt_b(const void* __restrict__ in, const int* __restrict__ isf32,
                        u16* __restrict__ out, int N){
  int i = blockIdx.x*256 + threadIdx.x;           // 0 .. N*16-1
  if (i >= N*16) return;
  int r = i >> 4, part = i & 15;                  // feats part*8 .. part*8+7
  u16x8 o;
  if (*isf32){
    const f32x4* p = (const f32x4*)in + (size_t)i*2;
    f32x4 v0 = p[0], v1 = p[1];
    #pragma unroll
    for (int k = 0; k < 4; k++){ o[k] = f2bf(v0[k]); o[k+4] = f2bf(v1[k]); }
  } else {
    o = *((const u16x8*)in + i);
  }
  int slice = part >> 2, elem = (part & 3)*8;
  __builtin_nontemporal_store(o, (u16x8*)(out + ((size_t)slice*N + r)*32 + elem));
}

// Swizzle W[128][128] x3 (dual dtype) into MFMA B-fragment order
__global__ void k_swz3(const void* W1, const void* W2, const void* W3,
                       const int* __restrict__ isf32, u16* __restrict__ WL){
  int l = blockIdx.x >> 6;
  const void* W = (l == 0) ? W1 : ((l == 1) ? W2 : W3);
  int idx = (blockIdx.x & 63)*256 + threadIdx.x;   // 0..16383
  int j    = idx & 7;
  int lane = (idx >> 3) & 63;
  int kb   = (idx >> 9) & 3;
  int ct   = idx >> 11;
  int m = lane & 15, q = lane >> 4;
  int k = kb*32 + q*8 + j;
  int c = ct*16 + m;
  float v = (*isf32) ? ((const float*)W)[k*F + c] : bf2f(((const u16*)W)[k*F + c]);
  WL[l*16384 + idx] = f2bf(v);
}

// G_t[c][N+1][32] = dis[r]*(X@W); sliced in, sliced out (G slice stride N+1).
__launch_bounds__(256)
__global__ void k_mm(const u16* __restrict__ X, const u16* __restrict__ WL,
                     const float* __restrict__ dis, u16* __restrict__ G, int N){
  int w = threadIdx.x >> 6, lane = threadIdx.x & 63;
  int m = lane & 15, q = lane >> 4;
  int row0 = blockIdx.x*64 + w*16;
  int arow = row0 + m;
  bf16x8 a[4];
  if (arow < N){
    #pragma unroll
    for (int kb = 0; kb < 4; kb++)
      a[kb] = *(const bf16x8*)(X + ((size_t)kb*N + arow)*32 + q*8);
  } else {
    #pragma unroll
    for (int kb = 0; kb < 4; kb++) a[kb] = (bf16x8){0,0,0,0,0,0,0,0};
  }
  f32x4 acc[8];
  #pragma unroll
  for (int ct = 0; ct < 8; ct++) acc[ct] = (f32x4){0.f,0.f,0.f,0.f};
  #pragma unroll
  for (int ct = 0; ct < 8; ct++){
    #pragma unroll
    for (int kb = 0; kb < 4; kb++){
      bf16x8 b = *(const bf16x8*)(WL + ((size_t)((ct*4 + kb)*64 + lane))*8);
      acc[ct] = __builtin_amdgcn_mfma_f32_16x16x32_bf16(a[kb], b, acc[ct], 0, 0, 0);
    }
  }
  int rbase = row0 + q*4;
  #pragma unroll
  for (int r = 0; r < 4; r++){
    int row = rbase + r;
    if (row < N){
      float dv = dis[row];
      #pragma unroll
      for (int ct = 0; ct < 8; ct++)
        __builtin_nontemporal_store(f2bf(dv*acc[ct][r]),
            &G[((size_t)(ct >> 1)*(N+1) + row)*32 + (ct & 1)*16 + m]);
    }
  }
}

// XCD-pinned sliced aggregation v2: slice c = (blockIdx&7)>>1 pinned to an
// XCD-pair (round-robin block->XCD, validated in R1: FETCH 150->24MB).
// lane = slot(4)x16 + fp(16); one load instr = 4 neighbor rows x 64B.
// 3-stage static-register pipeline: csr 2 supers ahead, G 1 super ahead.
// Masked slots redirect to a zeroed 64B row (maskless inner loop).
__launch_bounds__(256)
__global__ void k_agg(const u16* __restrict__ G, const float* __restrict__ dis,
                      const int* __restrict__ rs, const int* __restrict__ deg,
                      const u16* __restrict__ csr, const float* __restrict__ bias,
                      u16* __restrict__ Xout, int N, int relu){
  int b = blockIdx.x;
  int c = (b & 7) >> 1;                           // slice 0..3
  int wv = threadIdx.x >> 6;
  int lane = threadIdx.x & 63;
  int slot = lane >> 4, fp = lane & 15;
  int wid0 = (b >> 3)*16 + (b & 1)*8 + wv;
  const char* Gb = (const char*)G;
  u32 cb32 = (u32)((u32)c*(u32)(N+1)*64u);        // slice byte base (<=9.6MB)
  u32 zo   = (u32)((u32)(3*(N+1) + N)*64u);       // absolute zero-row byte off
  u32 fo   = ((u32)fp) << 2;
  float bv0 = bias[c*32 + 2*fp], bv1 = bias[c*32 + 2*fp + 1];

  #pragma unroll 2
  for (int t = 0; t < 2; t++){
    int wid = wid0 + 4*t;
    if (wid >= N) break;
    int base = rs[wid], len = deg[wid];
    float a0 = 0.f, a1 = 0.f;
    if (len > 0){
      const u16* cp = csr + base + slot;
      int nsg = (len + 15) >> 4;                  // 16-neighbor super-groups
      u32 cP0,cP1,cP2,cP3, cQ0,cQ1,cQ2,cQ3;
      u32 wP0,wP1,wP2,wP3, wQ0,wQ1,wQ2,wQ3;
      // prime: S(0)->P, S(1)->Q (csr pad makes OOB reads safe)
      cP0 = cp[0];  cP1 = cp[4];  cP2 = cp[8];  cP3 = cp[12];
      cQ0 = cp[16]; cQ1 = cp[20]; cQ2 = cp[24]; cQ3 = cp[28];
      // A(0) from P
      {
        int nb = slot;
        u32 o0 = (nb      < len) ? (cb32 + (cP0 << 6)) : zo;
        u32 o1 = (nb + 4  < len) ? (cb32 + (cP1 << 6)) : zo;
        u32 o2 = (nb + 8  < len) ? (cb32 + (cP2 << 6)) : zo;
        u32 o3 = (nb + 12 < len) ? (cb32 + (cP3 << 6)) : zo;
        wP0 = *(const u32*)(Gb + o0 + fo);
        wP1 = *(const u32*)(Gb + o1 + fo);
        wP2 = *(const u32*)(Gb + o2 + fo);
        wP3 = *(const u32*)(Gb + o3 + fo);
      }
      int s = 0;
      while (true){
        // ---- body P: A(s+1) from Q; S(s+2)->P; consume wP
        if (s + 1 < nsg){
          int nb = (s+1)*16 + slot;
          u32 o0 = (nb      < len) ? (cb32 + (cQ0 << 6)) : zo;
          u32 o1 = (nb + 4  < len) ? (cb32 + (cQ1 << 6)) : zo;
          u32 o2 = (nb + 8  < len) ? (cb32 + (cQ2 << 6)) : zo;
          u32 o3 = (nb + 12 < len) ? (cb32 + (cQ3 << 6)) : zo;
          wQ0 = *(const u32*)(Gb + o0 + fo);
          wQ1 = *(const u32*)(Gb + o1 + fo);
          wQ2 = *(const u32*)(Gb + o2 + fo);
          wQ3 = *(const u32*)(Gb + o3 + fo);
        }
        { const u16* c2 = cp + (s+2)*16;
          cP0 = c2[0]; cP1 = c2[4]; cP2 = c2[8]; cP3 = c2[12]; }
        a0 += bflo(wP0); a1 += bfhi(wP0);
        a0 += bflo(wP1); a1 += bfhi(wP1);
        a0 += bflo(wP2); a1 += bfhi(wP2);
        a0 += bflo(wP3); a1 += bfhi(wP3);
        s++;
        if (s >= nsg) break;
        // ---- body Q: A(s+1) from P; S(s+2)->Q; consume wQ
        if (s + 1 < nsg){
          int nb = (s+1)*16 + slot;
          u32 o0 = (nb      < len) ? (cb32 + (cP0 << 6)) : zo;
          u32 o1 = (nb + 4  < len) ? (cb32 + (cP1 << 6)) : zo;
          u32 o2 = (nb + 8  < len) ? (cb32 + (cP2 << 6)) : zo;
          u32 o3 = (nb + 12 < len) ? (cb32 + (cP3 << 6)) : zo;
          wP0 = *(const u32*)(Gb + o0 + fo);
          wP1 = *(const u32*)(Gb + o1 + fo);
          wP2 = *(const u32*)(Gb + o2 + fo);
          wP3 = *(const u32*)(Gb + o3 + fo);
        }
        { const u16* c2 = cp + (s+2)*16;
          cQ0 = c2[0]; cQ1 = c2[4]; cQ2 = c2[8]; cQ3 = c2[12]; }
        a0 += bflo(wQ0); a1 += bfhi(wQ0);
        a0 += bflo(wQ1); a1 += bfhi(wQ1);
        a0 += bflo(wQ2); a1 += bfhi(wQ2);
        a0 += bflo(wQ3); a1 += bfhi(wQ3);
        s++;
        if (s >= nsg) break;
      }
    }
    // fold slots (0..3 hold neighbors n === slot mod 4)
    a0 += __shfl_xor(a0, 16, 64); a0 += __shfl_xor(a0, 32, 64);
    a1 += __shfl_xor(a1, 16, 64); a1 += __shfl_xor(a1, 32, 64);
    if (slot == 0){
      u32 sw = *(const u32*)(Gb + cb32 + (((u32)wid) << 6) + fo);   // self row
      a0 += bflo(sw); a1 += bfhi(sw);
      float dv = dis[wid];
      float o0 = fmaf(dv, a0, bv0);
      float o1 = fmaf(dv, a1, bv1);
      if (relu){ o0 = fmaxf(o0, 0.f); o1 = fmaxf(o1, 0.f); }
      u32 pk = (u32)f2bf(o0) | ((u32)f2bf(o1) << 16);
      __builtin_nontemporal_store(pk,
          (u32*)((char*)Xout + (size_t)c*N*64 + (((size_t)wid) << 6) + fo));
    }
  }
}

// layer 4 matmul: G4[n] = dis[n] * dot(X_t[:,n,:], W4f); one wave per node
__global__ void k_mm4(const u16* __restrict__ X, const float* __restrict__ W4f,
                      const float* __restrict__ dis, float* __restrict__ G4, int N){
  int gt   = blockIdx.x*blockDim.x + threadIdx.x;
  int wid  = gt >> 6;
  int lane = threadIdx.x & 63;
  if (wid >= N) return;
  u32 xw = *(const u32*)(X + ((size_t)(lane >> 4)*N + wid)*32 + 2*(lane & 15));
  float acc = bflo(xw)*W4f[2*lane] + bfhi(xw)*W4f[2*lane + 1];
  #pragma unroll
  for (int off = 32; off > 0; off >>= 1) acc += __shfl_down(acc, off, 64);
  if (lane == 0) G4[wid] = dis[wid]*acc;
}

__global__ void k_agg4(const float* __restrict__ G4, const float* __restrict__ dis,
                       const int* __restrict__ rs, const int* __restrict__ deg,
                       const u16* __restrict__ csr, const float* __restrict__ b4f,
                       const int* __restrict__ isf32, void* __restrict__ out, int N){
  int i = blockIdx.x*blockDim.x + threadIdx.x;
  if (i >= N) return;
  int base = rs[i], len = deg[i];
  float a0 = 0.f, a1 = 0.f, a2 = 0.f, a3 = 0.f;
  int j = 0;
  for (; j + 4 <= len; j += 4){
    int s0 = csr[base + j],     s1 = csr[base + j + 1];
    int s2 = csr[base + j + 2], s3 = csr[base + j + 3];
    a0 += G4[s0]; a1 += G4[s1]; a2 += G4[s2]; a3 += G4[s3];
  }
  for (; j < len; j++) a0 += G4[csr[base + j]];
  float r = dis[i]*(G4[i] + ((a0 + a1) + (a2 + a3))) + b4f[0];
  if (*isf32) ((float*)out)[i] = r;
  else        ((u16*)out)[i]   = f2bf(r);
}

extern "C" void kernel_launch(void* const* d_in, const int* in_sizes, int n_in,
                              void* d_out, int out_size, void* d_ws, size_t ws_size,
                              hipStream_t stream){
  const void* x0 = d_in[0];
  const u32*  ei = (const u32*)d_in[1];
  const void* Wp[4] = {d_in[2], d_in[4], d_in[6], d_in[8]};
  const void* bp[4] = {d_in[3], d_in[5], d_in[7], d_in[9]};
  int N = in_sizes[0] / F;       // 50000
  int E = in_sizes[1] / 2;       // 1,600,000
  int NB = (N + 255) >> 8;       // 196 buckets

  char* base = (char*)d_ws;
  size_t off = 0;
  auto alloc = [&](size_t bytes)->char*{
    char* p = base + off;
    off = (off + bytes + 255) & ~(size_t)255;
    return p;
  };
  int*   deg  = (int*)  alloc((size_t)N*4);
  float* dis  = (float*)alloc((size_t)N*4);
  int*   rs   = (int*)  alloc((size_t)N*4);
  float* g4   = (float*)alloc((size_t)N*4);
  int*   bcnt = (int*)  alloc(1024);
  int*   bbase= (int*)  alloc(1056);           // 257 ints
  int*   bump = (int*)  alloc(1024);
  int*   flags= (int*)  alloc(256);            // [0]=int32-edge flag, [1]=isf32
  u32*   ebuf = (u32*)  alloc((size_t)E*4);    // bucketed packed edges, 6.4 MB
  u16*   csr  = (u16*)  alloc((size_t)(E+128)*2);  // +128-entry pad for pipeline
  u16*   WL   = (u16*)  alloc(3*16384*2);      // swizzled W1..W3, 96 KB
  float* wf4  = (float*)alloc(F*4);
  float* bb   = (float*)alloc(3*F*4);          // biases b1..b3
  float* bb4  = (float*)alloc(256);
  u16*   gbuf = (u16*)  alloc((size_t)4*(N+1)*64); // 12.8 MB, sliced [4][N+1][32]
  u16*   xbuf = (u16*)  alloc((size_t)N*F*2);  // 12.8 MB, sliced [4][N][32]

  hipMemsetAsync(bcnt, 0, 1024, stream);
  hipMemsetAsync(flags, 0, 256, stream);
  hipMemsetAsync(gbuf + ((size_t)3*(N+1) + N)*32, 0, 64, stream);  // zero row

  int* eflag = flags + 0;
  int* isf32 = flags + 1;

  int nbt = (N + 255)/256;
  int etb = (E + 4095)/4096;

  k_flags <<<2, 256, 0, stream>>>((const u32*)x0, ei, flags);
  k_bhist <<<etb, 256, 0, stream>>>(ei, E, eflag, NB, bcnt);
  k_bscan <<<1, 256, 0, stream>>>(bcnt, NB, E, bbase, bump);
  k_msplit<<<etb, 256, 0, stream>>>(ei, E, eflag, bbase, bump, ebuf);
  k_bemit <<<NB, 256, 0, stream>>>(ebuf, bbase, N, deg, rs, csr, dis);
  k_prep  <<<1, 640, 0, stream>>>(bp[0], bp[1], bp[2], Wp[3], bp[3], isf32, bb, wf4, bb4);
  k_swz3  <<<192, 256, 0, stream>>>(Wp[0], Wp[1], Wp[2], isf32, WL);
  k_cvt_b <<<(N*16 + 255)/256, 256, 0, stream>>>(x0, isf32, xbuf, N);

  int mmb  = (N + 63)/64;
  int aggB = ((N + 15)/16)*8;    // 8 blocks cover 16 nodes x 4 slices

  for (int l = 0; l < 3; l++){
    k_mm <<<mmb, 256, 0, stream>>>(xbuf, WL + l*16384, dis, gbuf, N);
    k_agg<<<aggB, 256, 0, stream>>>(gbuf, dis, rs, deg, csr, bb + l*F, xbuf, N, 1);
  }
  k_mm4 <<<((size_t)N*64 + 255)/256, 256, 0, stream>>>(xbuf, wf4, dis, g4, N);
  k_agg4<<<nbt, 256, 0, stream>>>(g4, dis, rs, deg, csr, bb4, isf32, (void*)d_out, N);
}

// Round 4
// 412.785 us; speedup vs baseline: 1.0536x; 1.0536x over previous
//
#include <hip/hip_runtime.h>
#include <hip/hip_bf16.h>
#include <stdint.h>

typedef unsigned int u32;
typedef unsigned short u16;

#define F 128

typedef __attribute__((ext_vector_type(8))) short bf16x8;
typedef __attribute__((ext_vector_type(8))) u16 u16x8;
typedef __attribute__((ext_vector_type(4))) float f32x4;

__device__ __forceinline__ float bf2f(u16 v){
  union { u32 u; float f; } x; x.u = ((u32)v) << 16; return x.f;
}
__device__ __forceinline__ float bflo(u32 w){
  union { u32 u; float f; } x; x.u = w << 16; return x.f;       // 1 VALU
}
__device__ __forceinline__ float bfhi(u32 w){
  union { u32 u; float f; } x; x.u = w & 0xFFFF0000u; return x.f; // 1 VALU
}
__device__ __forceinline__ u16 f2bf(float f){
  union { float f; u32 u; } x; x.f = f;
  u32 u = x.u;
  return (u16)((u + 0x7fffu + ((u >> 16) & 1u)) >> 16);   // RNE
}

// ---- merged dtype / edge-layout detection -----------------------------------
__global__ void k_flags(const u32* __restrict__ xw, const u32* __restrict__ ei,
                        int* __restrict__ flags){
  if (blockIdx.x == 0){
    u32 hit = 0;
    for (int i = threadIdx.x; i < 2048; i += 256){
      u32 e = (xw[i] >> 7) & 0xFFu;
      if (e > 160u) hit = 1;
    }
    if (hit) atomicOr(&flags[1], 1);
  } else {
    u32 v = 0;
    for (int i = threadIdx.x; i < 4096; i += 256) v |= ei[2*i + 1];
    if (v) atomicOr(&flags[0], 1);
  }
}

// ---- bucketed CSR build (256-node buckets) ----------------------------------
__launch_bounds__(256)
__global__ void k_bhist(const u32* __restrict__ w, int E, const int* __restrict__ flagp,
                        int NB, int* __restrict__ bcnt){
  __shared__ int h[256];
  int st = (*flagp) ? 1 : 2;
  int t = threadIdx.x;
  h[t] = 0;
  __syncthreads();
  int base = blockIdx.x*4096;
  #pragma unroll 4
  for (int k = 0; k < 16; k++){
    int i = base + k*256 + t;
    if (i < E){
      int d = (int)w[(size_t)(E + i)*st];
      atomicAdd(&h[d >> 8], 1);
    }
  }
  __syncthreads();
  if (t < NB && h[t]) atomicAdd(&bcnt[t], h[t]);
}

__global__ void k_bscan(const int* __restrict__ bcnt, int NB, int E,
                        int* __restrict__ bbase, int* __restrict__ bump){
  __shared__ int s[256];
  int t = threadIdx.x;
  int v = (t < NB) ? bcnt[t] : 0;
  s[t] = v;
  __syncthreads();
  for (int off = 1; off < 256; off <<= 1){
    int x = (t >= off) ? s[t - off] : 0;
    __syncthreads();
    s[t] += x;
    __syncthreads();
  }
  bbase[t] = s[t] - v;            // exclusive; == E for t >= NB
  if (t == 255) bbase[256] = E;
  bump[t] = 0;
}

__launch_bounds__(256)
__global__ void k_msplit(const u32* __restrict__ w, int E, const int* __restrict__ flagp,
                         const int* __restrict__ bbase, int* __restrict__ bump,
                         u32* __restrict__ ebuf){
  __shared__ int h[256];
  __shared__ int cb[256];
  int st = (*flagp) ? 1 : 2;
  int t = threadIdx.x;
  h[t] = 0;
  __syncthreads();
  int base = blockIdx.x*4096;
  u32 ps[16]; int bk[16]; int rk[16];
  #pragma unroll 4
  for (int k = 0; k < 16; k++){
    int i = base + k*256 + t;
    if (i < E){
      u32 s = w[(size_t)i*st];
      u32 d = w[(size_t)(E + i)*st];
      bk[k] = (int)(d >> 8);
      ps[k] = (s & 0xFFFFu) | ((d & 0xFFu) << 16);
      rk[k] = atomicAdd(&h[bk[k]], 1);
    } else bk[k] = -1;
  }
  __syncthreads();
  cb[t] = h[t] ? (bbase[t] + atomicAdd(&bump[t], h[t])) : 0;
  __syncthreads();
  #pragma unroll 4
  for (int k = 0; k < 16; k++){
    if (bk[k] >= 0) ebuf[cb[bk[k]] + rk[k]] = ps[k];
  }
}

// per-bucket deg/rs/csr32 emit; csr32 entries are PRE-SHIFTED byte offsets
// (src<<6 = slice-row byte offset). Each node's region is 4-entry aligned so
// every slot quad is a 16B-aligned dwordx4. dis folded in.
__launch_bounds__(256)
__global__ void k_bemit(const u32* __restrict__ ebuf, const int* __restrict__ bbase,
                        int N, int* __restrict__ deg, int* __restrict__ rs,
                        u32* __restrict__ csr32, float* __restrict__ dis){
  __shared__ int nd[256];
  __shared__ int nofs[256];
  __shared__ int s[256];
  int b = blockIdx.x;
  int t = threadIdx.x;
  int e0 = bbase[b], e1 = bbase[b + 1];
  int pb = e0 + b*1024;                 // padded bucket base (<=768 pad used)
  nd[t] = 0;
  __syncthreads();
  for (int i = e0 + t; i < e1; i += 256) atomicAdd(&nd[ebuf[i] >> 16], 1);
  __syncthreads();
  int v = nd[t];
  int pv = (v + 3) & ~3;                // 4-entry aligned node region
  s[t] = pv;
  __syncthreads();
  for (int off = 1; off < 256; off <<= 1){
    int x = (t >= off) ? s[t - off] : 0;
    __syncthreads();
    s[t] += x;
    __syncthreads();
  }
  nofs[t] = s[t] - pv;
  int node = b*256 + t;
  if (node < N){
    deg[node] = v;
    rs[node]  = pb + nofs[t];
    dis[node] = rsqrtf(1.0f + (float)v);
  }
  nd[t] = 0;               // reuse as fill
  __syncthreads();
  for (int i = e0 + t; i < e1; i += 256){
    u32 p = ebuf[i];
    int d = (int)(p >> 16);
    int pos = pb + nofs[d] + atomicAdd(&nd[d], 1);
    csr32[pos] = (p & 0xFFFFu) << 6;
  }
}

// ---- merged small-tensor prep: bb[3][128], wf4[128], bb4[1] -----------------
__global__ void k_prep(const void* b1, const void* b2, const void* b3,
                       const void* W4, const void* b4, const int* __restrict__ isf32,
                       float* __restrict__ bb, float* __restrict__ wf4,
                       float* __restrict__ bb4){
  int t = threadIdx.x;
  int f32 = *isf32;
  if (t < 384){
    const void* s = (t < 128) ? b1 : ((t < 256) ? b2 : b3);
    int i = t & 127;
    bb[t] = f32 ? ((const float*)s)[i] : bf2f(((const u16*)s)[i]);
  } else if (t < 512){
    int i = t - 384;
    wf4[i] = f32 ? ((const float*)W4)[i] : bf2f(((const u16*)W4)[i]);
  } else if (t == 512){
    bb4[0] = f32 ? ((const float*)b4)[0] : bf2f(((const u16*)b4)[0]);
  }
}

// dual-dtype input -> bf16 in SLICED layout X_t[c][r][32]; thread = 8 feats
__global__ void k_cvt_b(const void* __restrict__ in, const int* __restrict__ isf32,
                        u16* __restrict__ out, int N){
  int i = blockIdx.x*256 + threadIdx.x;           // 0 .. N*16-1
  if (i >= N*16) return;
  int r = i >> 4, part = i & 15;                  // feats part*8 .. part*8+7
  u16x8 o;
  if (*isf32){
    const f32x4* p = (const f32x4*)in + (size_t)i*2;
    f32x4 v0 = p[0], v1 = p[1];
    #pragma unroll
    for (int k = 0; k < 4; k++){ o[k] = f2bf(v0[k]); o[k+4] = f2bf(v1[k]); }
  } else {
    o = *((const u16x8*)in + i);
  }
  int slice = part >> 2, elem = (part & 3)*8;
  __builtin_nontemporal_store(o, (u16x8*)(out + ((size_t)slice*N + r)*32 + elem));
}

// Swizzle W[128][128] x3 (dual dtype) into MFMA B-fragment order
__global__ void k_swz3(const void* W1, const void* W2, const void* W3,
                       const int* __restrict__ isf32, u16* __restrict__ WL){
  int l = blockIdx.x >> 6;
  const void* W = (l == 0) ? W1 : ((l == 1) ? W2 : W3);
  int idx = (blockIdx.x & 63)*256 + threadIdx.x;   // 0..16383
  int j    = idx & 7;
  int lane = (idx >> 3) & 63;
  int kb   = (idx >> 9) & 3;
  int ct   = idx >> 11;
  int m = lane & 15, q = lane >> 4;
  int k = kb*32 + q*8 + j;
  int c = ct*16 + m;
  float v = (*isf32) ? ((const float*)W)[k*F + c] : bf2f(((const u16*)W)[k*F + c]);
  WL[l*16384 + idx] = f2bf(v);
}

// G_t[c][N+1][32] = dis[r]*(X@W); sliced in, sliced out (G slice stride N+1).
__launch_bounds__(256)
__global__ void k_mm(const u16* __restrict__ X, const u16* __restrict__ WL,
                     const float* __restrict__ dis, u16* __restrict__ G, int N){
  int w = threadIdx.x >> 6, lane = threadIdx.x & 63;
  int m = lane & 15, q = lane >> 4;
  int row0 = blockIdx.x*64 + w*16;
  int arow = row0 + m;
  bf16x8 a[4];
  if (arow < N){
    #pragma unroll
    for (int kb = 0; kb < 4; kb++)
      a[kb] = *(const bf16x8*)(X + ((size_t)kb*N + arow)*32 + q*8);
  } else {
    #pragma unroll
    for (int kb = 0; kb < 4; kb++) a[kb] = (bf16x8){0,0,0,0,0,0,0,0};
  }
  f32x4 acc[8];
  #pragma unroll
  for (int ct = 0; ct < 8; ct++) acc[ct] = (f32x4){0.f,0.f,0.f,0.f};
  #pragma unroll
  for (int ct = 0; ct < 8; ct++){
    #pragma unroll
    for (int kb = 0; kb < 4; kb++){
      bf16x8 b = *(const bf16x8*)(WL + ((size_t)((ct*4 + kb)*64 + lane))*8);
      acc[ct] = __builtin_amdgcn_mfma_f32_16x16x32_bf16(a[kb], b, acc[ct], 0, 0, 0);
    }
  }
  int rbase = row0 + q*4;
  #pragma unroll
  for (int r = 0; r < 4; r++){
    int row = rbase + r;
    if (row < N){
      float dv = dis[row];
      #pragma unroll
      for (int ct = 0; ct < 8; ct++)
        __builtin_nontemporal_store(f2bf(dv*acc[ct][r]),
            &G[((size_t)(ct >> 1)*(N+1) + row)*32 + (ct & 1)*16 + m]);
    }
  }
}

// XCD-pinned sliced aggregation v3: slice c = (blockIdx&7)>>1 (validated:
// FETCH 150->24MB). lane = slot(4)x16 + fp(16); one load instr = 4 rows x 64B.
// csr32 entries pre-shifted (<<6): per slot 1 dwordx4 covers its 4 edges of a
// 16-edge group; addressing = 1 v_add per gather (SGPR slice base + u32 off).
// Full groups maskless; only the tail group pays cmp+cndmask. csr quad
// prefetched one group ahead (always-read; overread lands in valid pad).
__launch_bounds__(256)
__global__ void k_agg(const u16* __restrict__ G, const float* __restrict__ dis,
                      const int* __restrict__ rs, const int* __restrict__ deg,
                      const u32* __restrict__ csr32, const float* __restrict__ bias,
                      u16* __restrict__ Xout, int N, int relu){
  int b = blockIdx.x;
  int c = (b & 7) >> 1;                           // slice 0..3
  int wv = threadIdx.x >> 6;
  int lane = threadIdx.x & 63;
  int slot = lane >> 4, fp = lane & 15;
  int wid0 = (b >> 3)*16 + (b & 1)*8 + wv;
  const char* Gs = (const char*)G + (size_t)c*(size_t)(N+1)*64;  // slice base
  const char* Cb = (const char*)csr32;
  u32 zoff = ((u32)N) << 6;                       // zeroed pad row of slice
  u32 fo   = ((u32)fp) << 2;
  float bv0 = bias[c*32 + 2*fp], bv1 = bias[c*32 + 2*fp + 1];

  #pragma unroll 2
  for (int t = 0; t < 2; t++){
    int wid = wid0 + 4*t;
    if (wid >= N) break;
    int base = rs[wid], len = deg[wid];
    float a0 = 0.f, a1 = 0.f;
    if (len > 0){
      u32 coff = ((u32)base << 2) + ((u32)slot << 4);
      int nfull = len >> 4, rem = len & 15;
      uint4 q = *(const uint4*)(Cb + coff); coff += 64;
      for (int s = 0; s < nfull; s++){
        uint4 qn = *(const uint4*)(Cb + coff); coff += 64;   // prefetch next
        u32 w0 = *(const u32*)(Gs + (q.x + fo));
        u32 w1 = *(const u32*)(Gs + (q.y + fo));
        u32 w2 = *(const u32*)(Gs + (q.z + fo));
        u32 w3 = *(const u32*)(Gs + (q.w + fo));
        a0 += bflo(w0); a1 += bfhi(w0);
        a0 += bflo(w1); a1 += bfhi(w1);
        a0 += bflo(w2); a1 += bfhi(w2);
        a0 += bflo(w3); a1 += bfhi(w3);
        q = qn;
      }
      if (rem){
        int sb = slot << 2;                        // idx<len <=> sb+k < rem
        u32 o0 = ((sb + 0 < rem) ? q.x : zoff) + fo;
        u32 o1 = ((sb + 1 < rem) ? q.y : zoff) + fo;
        u32 o2 = ((sb + 2 < rem) ? q.z : zoff) + fo;
        u32 o3 = ((sb + 3 < rem) ? q.w : zoff) + fo;
        u32 w0 = *(const u32*)(Gs + o0);
        u32 w1 = *(const u32*)(Gs + o1);
        u32 w2 = *(const u32*)(Gs + o2);
        u32 w3 = *(const u32*)(Gs + o3);
        a0 += bflo(w0); a1 += bfhi(w0);
        a0 += bflo(w1); a1 += bfhi(w1);
        a0 += bflo(w2); a1 += bfhi(w2);
        a0 += bflo(w3); a1 += bfhi(w3);
      }
    }
    // fold slots
    a0 += __shfl_xor(a0, 16, 64); a0 += __shfl_xor(a0, 32, 64);
    a1 += __shfl_xor(a1, 16, 64); a1 += __shfl_xor(a1, 32, 64);
    if (slot == 0){
      u32 sw = *(const u32*)(Gs + ((((u32)wid) << 6) + fo));   // self row
      a0 += bflo(sw); a1 += bfhi(sw);
      float dv = dis[wid];
      float o0 = fmaf(dv, a0, bv0);
      float o1 = fmaf(dv, a1, bv1);
      if (relu){ o0 = fmaxf(o0, 0.f); o1 = fmaxf(o1, 0.f); }
      u32 pk = (u32)f2bf(o0) | ((u32)f2bf(o1) << 16);
      __builtin_nontemporal_store(pk,
          (u32*)((char*)Xout + (size_t)c*N*64 + (((size_t)wid) << 6) + fo));
    }
  }
}

// layer 4 matmul: G4[n] = dis[n] * dot(X_t[:,n,:], W4f); one wave per node
__global__ void k_mm4(const u16* __restrict__ X, const float* __restrict__ W4f,
                      const float* __restrict__ dis, float* __restrict__ G4, int N){
  int gt   = blockIdx.x*blockDim.x + threadIdx.x;
  int wid  = gt >> 6;
  int lane = threadIdx.x & 63;
  if (wid >= N) return;
  u32 xw = *(const u32*)(X + ((size_t)(lane >> 4)*N + wid)*32 + 2*(lane & 15));
  float acc = bflo(xw)*W4f[2*lane] + bfhi(xw)*W4f[2*lane + 1];
  #pragma unroll
  for (int off = 32; off > 0; off >>= 1) acc += __shfl_down(acc, off, 64);
  if (lane == 0) G4[wid] = dis[wid]*acc;
}

__global__ void k_agg4(const float* __restrict__ G4, const float* __restrict__ dis,
                       const int* __restrict__ rs, const int* __restrict__ deg,
                       const u32* __restrict__ csr32, const float* __restrict__ b4f,
                       const int* __restrict__ isf32, void* __restrict__ out, int N){
  int i = blockIdx.x*blockDim.x + threadIdx.x;
  if (i >= N) return;
  int base = rs[i], len = deg[i];
  const char* Gb = (const char*)G4;
  float a0 = 0.f, a1 = 0.f, a2 = 0.f, a3 = 0.f;
  int j = 0;
  for (; j + 4 <= len; j += 4){
    u32 e0 = csr32[base + j],     e1 = csr32[base + j + 1];
    u32 e2 = csr32[base + j + 2], e3 = csr32[base + j + 3];
    a0 += *(const float*)(Gb + (e0 >> 4));   // (src<<6)>>4 = src*4
    a1 += *(const float*)(Gb + (e1 >> 4));
    a2 += *(const float*)(Gb + (e2 >> 4));
    a3 += *(const float*)(Gb + (e3 >> 4));
  }
  for (; j < len; j++) a0 += *(const float*)(Gb + (csr32[base + j] >> 4));
  float r = dis[i]*(G4[i] + ((a0 + a1) + (a2 + a3))) + b4f[0];
  if (*isf32) ((float*)out)[i] = r;
  else        ((u16*)out)[i]   = f2bf(r);
}

extern "C" void kernel_launch(void* const* d_in, const int* in_sizes, int n_in,
                              void* d_out, int out_size, void* d_ws, size_t ws_size,
                              hipStream_t stream){
  const void* x0 = d_in[0];
  const u32*  ei = (const u32*)d_in[1];
  const void* Wp[4] = {d_in[2], d_in[4], d_in[6], d_in[8]};
  const void* bp[4] = {d_in[3], d_in[5], d_in[7], d_in[9]};
  int N = in_sizes[0] / F;       // 50000
  int E = in_sizes[1] / 2;       // 1,600,000
  int NB = (N + 255) >> 8;       // 196 buckets

  char* base = (char*)d_ws;
  size_t off = 0;
  auto alloc = [&](size_t bytes)->char*{
    char* p = base + off;
    off = (off + bytes + 255) & ~(size_t)255;
    return p;
  };
  int*   deg  = (int*)  alloc((size_t)N*4);
  float* dis  = (float*)alloc((size_t)N*4);
  int*   rs   = (int*)  alloc((size_t)N*4);
  float* g4   = (float*)alloc((size_t)N*4);
  int*   bcnt = (int*)  alloc(1024);
  int*   bbase= (int*)  alloc(1056);           // 257 ints
  int*   bump = (int*)  alloc(1024);
  int*   flags= (int*)  alloc(256);            // [0]=int32-edge flag, [1]=isf32
  u32*   ebuf = (u32*)  alloc((size_t)E*4);    // bucketed packed edges, 6.4 MB
  u32*   csr32= (u32*)  alloc(((size_t)E + (size_t)NB*1024 + 64)*4); // 7.2 MB
  u16*   WL   = (u16*)  alloc(3*16384*2);      // swizzled W1..W3, 96 KB
  float* wf4  = (float*)alloc(F*4);
  float* bb   = (float*)alloc(3*F*4);          // biases b1..b3
  float* bb4  = (float*)alloc(256);
  u16*   gbuf = (u16*)  alloc((size_t)4*(N+1)*64); // 12.8 MB, sliced [4][N+1][32]
  u16*   xbuf = (u16*)  alloc((size_t)N*F*2);  // 12.8 MB, sliced [4][N][32]

  hipMemsetAsync(bcnt, 0, 1024, stream);
  hipMemsetAsync(flags, 0, 256, stream);
  // zero pad row (node index N) of each of the 4 G slices
  for (int c = 0; c < 4; c++)
    hipMemsetAsync(gbuf + ((size_t)c*(N+1) + N)*32, 0, 64, stream);

  int* eflag = flags + 0;
  int* isf32 = flags + 1;

  int nbt = (N + 255)/256;
  int etb = (E + 4095)/4096;

  k_flags <<<2, 256, 0, stream>>>((const u32*)x0, ei, flags);
  k_bhist <<<etb, 256, 0, stream>>>(ei, E, eflag, NB, bcnt);
  k_bscan <<<1, 256, 0, stream>>>(bcnt, NB, E, bbase, bump);
  k_msplit<<<etb, 256, 0, stream>>>(ei, E, eflag, bbase, bump, ebuf);
  k_bemit <<<NB, 256, 0, stream>>>(ebuf, bbase, N, deg, rs, csr32, dis);
  k_prep  <<<1, 640, 0, stream>>>(bp[0], bp[1], bp[2], Wp[3], bp[3], isf32, bb, wf4, bb4);
  k_swz3  <<<192, 256, 0, stream>>>(Wp[0], Wp[1], Wp[2], isf32, WL);
  k_cvt_b <<<(N*16 + 255)/256, 256, 0, stream>>>(x0, isf32, xbuf, N);

  int mmb  = (N + 63)/64;
  int aggB = ((N + 15)/16)*8;    // 8 blocks cover 16 nodes x 4 slices

  for (int l = 0; l < 3; l++){
    k_mm <<<mmb, 256, 0, stream>>>(xbuf, WL + l*16384, dis, gbuf, N);
    k_agg<<<aggB, 256, 0, stream>>>(gbuf, dis, rs, deg, csr32, bb + l*F, xbuf, N, 1);
  }
  k_mm4 <<<((size_t)N*64 + 255)/256, 256, 0, stream>>>(xbuf, wf4, dis, g4, N);
  k_agg4<<<nbt, 256, 0, stream>>>(g4, dis, rs, deg, csr32, bb4, isf32, (void*)d_out, N);
}